// Round 1
// baseline (176.867 us; speedup 1.0000x reference)
//
#include <hip/hip_runtime.h>
#include <math.h>

#define BATCHES 32
#define NPTS 65536
#define CH 14
#define BLOCKS_PER_BATCH 64            // 2048 blocks = 8 blocks/CU -> 32 waves/CU (max occupancy)
#define NBLOCKS (BATCHES * BLOCKS_PER_BATCH)
#define THREADS 256
#define PPB (NPTS / BLOCKS_PER_BATCH)  // 1024 points per block
#define PAIRS (PPB / 2)                // 512 point-pairs per block
#define ITERS (PAIRS / THREADS)        // 2 pairs per thread

// Kernel 1: per-block 9-way moment reduction, written to a DISTINCT slot per
// block (no atomics, no zero-init needed -> the ws 0xAA poison is harmless and
// the hipMemsetAsync dispatch is eliminated).
//
// Load trick: two consecutive 56-B records form a 112-B, 16B-aligned pair.
//   float4 @ byte 0   -> x0 y0 z0 (w junk)
//   float4 @ byte 48  -> (junk junk) x1 y1
//   float  @ byte 64  -> z1
// 3 VMEM instrs / 2 points instead of 4; HBM fetch unchanged (every 64B line
// of the buffer contains needed bytes, so ~117 MB is the hard floor).
__global__ __launch_bounds__(THREADS) void moments_kernel(
    const float* __restrict__ g, float* __restrict__ partials) {
    const int b   = blockIdx.x >> 6;           // / BLOCKS_PER_BATCH
    const int blk = blockIdx.x & 63;           // % BLOCKS_PER_BATCH
    const float* pb = g + ((size_t)b * NPTS + (size_t)blk * PPB) * CH;

    float sx = 0.f, sy = 0.f, sz = 0.f;
    float sxx = 0.f, syy = 0.f, szz = 0.f;
    float sxy = 0.f, sxz = 0.f, syz = 0.f;

#pragma unroll
    for (int it = 0; it < ITERS; ++it) {
        const int p = it * THREADS + threadIdx.x;      // pair index in block
        const float* q = pb + (size_t)p * (2 * CH);    // 112B-aligned to 16B
        const float4 a = *(const float4*)(q);          // x0 y0 z0 .
        const float4 c = *(const float4*)(q + 12);     // .  .  x1 y1
        const float z1 = q[16];                        // z1
        const float x0 = a.x, y0 = a.y, z0 = a.z;
        const float x1 = c.z, y1 = c.w;
        sx += x0 + x1;
        sy += y0 + y1;
        sz += z0 + z1;
        sxx += x0 * x0 + x1 * x1;
        syy += y0 * y0 + y1 * y1;
        szz += z0 * z0 + z1 * z1;
        sxy += x0 * y0 + x1 * y1;
        sxz += x0 * z0 + x1 * z1;
        syz += y0 * z0 + y1 * z1;
    }

    float vals[9] = {sx, sy, sz, sxx, syy, szz, sxy, sxz, syz};
#pragma unroll
    for (int k = 0; k < 9; ++k) {
        float v = vals[k];
#pragma unroll
        for (int off = 32; off >= 1; off >>= 1)
            v += __shfl_down(v, off, 64);
        vals[k] = v;
    }

    __shared__ float red[THREADS / 64][9];
    const int wave = threadIdx.x >> 6;
    const int lane = threadIdx.x & 63;
    if (lane == 0) {
#pragma unroll
        for (int k = 0; k < 9; ++k) red[wave][k] = vals[k];
    }
    __syncthreads();
    if (threadIdx.x < 9) {
        const int k = threadIdx.x;
        partials[(size_t)blockIdx.x * 9 + k] =
            red[0][k] + red[1][k] + red[2][k] + red[3][k];
    }
}

// Kernel 2: per-batch fp64 partial-sum reduction + 3x3 symmetric eigensolve
// (closed form) + final mean.
__global__ __launch_bounds__(64) void finish_kernel(
    const float* __restrict__ partials, float* __restrict__ out) {
    __shared__ double logs[BATCHES];
    const int b = threadIdx.x;
    if (b < BATCHES) {
        double s[9] = {0, 0, 0, 0, 0, 0, 0, 0, 0};
        const float* p = partials + (size_t)b * BLOCKS_PER_BATCH * 9;
        for (int j = 0; j < BLOCKS_PER_BATCH; ++j) {
#pragma unroll
            for (int k = 0; k < 9; ++k) s[k] += (double)p[j * 9 + k];
        }
        const double invN = 1.0 / (double)NPTS;
        double mx = s[0] * invN, my = s[1] * invN, mz = s[2] * invN;
        double a00 = s[3] * invN - mx * mx;
        double a11 = s[4] * invN - my * my;
        double a22 = s[5] * invN - mz * mz;
        double a01 = s[6] * invN - mx * my;
        double a02 = s[7] * invN - mx * mz;
        double a12 = s[8] * invN - my * mz;
        // _sanitize: clamp to +-1e6 (inputs finite; NaN path not reachable)
        const double CL = 1e6;
        a00 = fmin(fmax(a00, -CL), CL); a11 = fmin(fmax(a11, -CL), CL);
        a22 = fmin(fmax(a22, -CL), CL); a01 = fmin(fmax(a01, -CL), CL);
        a02 = fmin(fmax(a02, -CL), CL); a12 = fmin(fmax(a12, -CL), CL);

        // closed-form eigenvalues of symmetric 3x3
        double q  = (a00 + a11 + a22) / 3.0;
        double p1 = a01 * a01 + a02 * a02 + a12 * a12;
        double b00 = a00 - q, b11 = a11 - q, b22 = a22 - q;
        double p2 = b00 * b00 + b11 * b11 + b22 * b22 + 2.0 * p1;
        double eigmax, eigmin;
        if (p2 <= 0.0) {
            eigmax = eigmin = q;
        } else {
            double pp = sqrt(p2 / 6.0);
            double ip = 1.0 / pp;
            double c00 = b00 * ip, c11 = b11 * ip, c22 = b22 * ip;
            double c01 = a01 * ip, c02 = a02 * ip, c12 = a12 * ip;
            double detB = c00 * (c11 * c22 - c12 * c12)
                        - c01 * (c01 * c22 - c12 * c02)
                        + c02 * (c01 * c12 - c11 * c02);
            double r = detB * 0.5;
            r = fmin(1.0, fmax(-1.0, r));
            double phi = acos(r) / 3.0;
            eigmax = q + 2.0 * pp * cos(phi);
            eigmin = q + 2.0 * pp * cos(phi + 2.0943951023931953);  // +2pi/3
        }
        double maxe = fmax(fmin(eigmax, 1e6), 1e-6);
        double mine = fmax(fmin(eigmin, 1e6), 1e-6);
        double ratio = maxe / mine;
        ratio = fmin(fmax(ratio, 1.0), 1e6);
        logs[b] = log(ratio);
    }
    __syncthreads();
    if (threadIdx.x == 0) {
        double acc = 0.0;
#pragma unroll
        for (int i = 0; i < BATCHES; ++i) acc += logs[i];
        out[0] = (float)(-acc / (double)BATCHES);
    }
}

extern "C" void kernel_launch(void* const* d_in, const int* in_sizes, int n_in,
                              void* d_out, int out_size, void* d_ws, size_t ws_size,
                              hipStream_t stream) {
    const float* g = (const float*)d_in[0];
    float* out = (float*)d_out;
    float* partials = (float*)d_ws;   // NBLOCKS*9 floats, all written every call

    moments_kernel<<<NBLOCKS, THREADS, 0, stream>>>(g, partials);
    finish_kernel<<<1, 64, 0, stream>>>(partials, out);
}